// Round 3
// baseline (227.376 us; speedup 1.0000x reference)
//
#include <hip/hip_runtime.h>
#include <cstdint>
#include <cmath>

typedef unsigned int uint;
typedef unsigned short ushort;
typedef __bf16 bf16_t;
typedef bf16_t bf16x8 __attribute__((ext_vector_type(8)));
typedef float f32x4 __attribute__((ext_vector_type(4)));
typedef float f32x16 __attribute__((ext_vector_type(16)));

#define LOG2E 1.44269504088896340736f

__device__ __forceinline__ ushort f2bf(float f) {
  uint x = __float_as_uint(f);
  x += 0x7fffu + ((x >> 16) & 1u);   // RNE to bf16
  return (ushort)(x >> 16);
}
__device__ __forceinline__ uint pack2(float lo, float hi) {
  return (uint)f2bf(lo) | ((uint)f2bf(hi) << 16);
}
__device__ __forceinline__ uint cvt_pk_bf16(float lo, float hi) {
  uint r;
  asm("v_cvt_pk_bf16_f32 %0, %1, %2" : "=v"(r) : "v"(lo), "v"(hi));
  return r;
}

// global -> LDS direct copy, 16B per lane; LDS dest is wave-uniform base + lane*16.
__device__ __forceinline__ void gload_lds16(const void* gsrc, void* ldsdst) {
  typedef const __attribute__((address_space(1))) unsigned int* gp_t;
  typedef __attribute__((address_space(3))) unsigned int* lp_t;
  __builtin_amdgcn_global_load_lds((gp_t)(uintptr_t)gsrc,
                                   (lp_t)(unsigned int)(uintptr_t)ldsdst,
                                   16, 0, 0);
}

// ---------------- fp32 -> bf16 converts ----------------
__global__ __launch_bounds__(256) void cvt_x(const float* __restrict__ src,
                                             ushort* __restrict__ dst, int n8) {
  int i = blockIdx.x * blockDim.x + threadIdx.x;
  if (i >= n8) return;
  const float4* s4 = (const float4*)src;
  float4 a = s4[i * 2], b = s4[i * 2 + 1];
  uint4 o;
  o.x = pack2(a.x, a.y); o.y = pack2(a.z, a.w);
  o.z = pack2(b.x, b.y); o.w = pack2(b.z, b.w);
  ((uint4*)dst)[i] = o;
}

// 4 weight matrices in one launch: y=0..2 -> Wqkvb slices, y=3 -> Wob
__global__ __launch_bounds__(256) void cvt_w4(const float* __restrict__ s0,
                                              const float* __restrict__ s1,
                                              const float* __restrict__ s2,
                                              const float* __restrict__ s3,
                                              ushort* __restrict__ dA,
                                              ushort* __restrict__ dB, int n8) {
  const int y = blockIdx.y;
  const float* src = (y == 0) ? s0 : (y == 1) ? s1 : (y == 2) ? s2 : s3;
  ushort* dst = (y < 3) ? (dA + (size_t)y * n8 * 8) : dB;
  int i = blockIdx.x * blockDim.x + threadIdx.x;
  if (i >= n8) return;
  const float4* s4 = (const float4*)src;
  float4 a = s4[i * 2], b = s4[i * 2 + 1];
  uint4 o;
  o.x = pack2(a.x, a.y); o.y = pack2(a.z, a.w);
  o.z = pack2(b.x, b.y); o.w = pack2(b.z, b.w);
  ((uint4*)dst)[i] = o;
}

// ---------------- fused QKV GEMM, m97 structure: 256 thr, 4 waves, 64x64/wave ----------
// C[m][n] = sum_k A[m][k]*B[n][k]; B rows 0..2047=Wq, 2048..4095=Wk, 4096..6143=Wv.
// q/k pre-activations -> fp32; V -> bf16 written transposed (Vt[d][s]).
__global__ __launch_bounds__(256) void gemm_qkv4(const ushort* __restrict__ A,
                                                 const ushort* __restrict__ B,
                                                 const float* __restrict__ bq,
                                                 const float* __restrict__ bk,
                                                 const float* __restrict__ bv,
                                                 float* __restrict__ qpre,
                                                 float* __restrict__ kpre,
                                                 ushort* __restrict__ Vt,
                                                 int K, int S_) {
  __shared__ __align__(16) unsigned char As[8192];
  __shared__ __align__(16) unsigned char Bs[8192];
  const int t = threadIdx.x, l = t & 63, w = t >> 6;
  const int g = l >> 4, c = l & 15;
  const int wr = w >> 1, wc = w & 1;

  const int nx = gridDim.x;
  const int nwg = nx * gridDim.y;
  const int orig = blockIdx.y * nx + blockIdx.x;
  const int lin = (orig & 7) * (nwg >> 3) + (orig >> 3);   // XCD-contiguous
  const int bx = lin % nx, by = lin / nx;
  const int tm = by * 128, tn = bx * 128;

  const int srow = t >> 2;
  const int schunk = (t & 3) ^ (srow & 3);
  const ushort* Ag = A + (size_t)(tm + srow) * K + schunk * 8;
  const ushort* Bg = B + (size_t)(tn + srow) * K + schunk * 8;
  const size_t rowK64 = (size_t)64 * K;
  void* As0 = (void*)(As + w * 1024);
  void* As1 = (void*)(As + 4096 + w * 1024);
  void* Bs0 = (void*)(Bs + w * 1024);
  void* Bs1 = (void*)(Bs + 4096 + w * 1024);

  f32x4 acc[4][4] = {};

  for (int kt = 0; kt < K; kt += 32) {
    __syncthreads();
    gload_lds16(Ag + kt, As0);
    gload_lds16(Ag + rowK64 + kt, As1);
    gload_lds16(Bg + kt, Bs0);
    gload_lds16(Bg + rowK64 + kt, Bs1);
    __syncthreads();
    bf16x8 af[4], bfr[4];
#pragma unroll
    for (int m = 0; m < 4; ++m) {
      int row = wr * 64 + m * 16 + c;
      af[m] = *(const bf16x8*)(As + row * 64 + ((g ^ (row & 3)) << 4));
    }
#pragma unroll
    for (int n = 0; n < 4; ++n) {
      int row = wc * 64 + n * 16 + c;
      bfr[n] = *(const bf16x8*)(Bs + row * 64 + ((g ^ (row & 3)) << 4));
    }
#pragma unroll
    for (int m = 0; m < 4; ++m)
#pragma unroll
      for (int n = 0; n < 4; ++n)
        acc[m][n] = __builtin_amdgcn_mfma_f32_16x16x32_bf16(af[m], bfr[n], acc[m][n], 0, 0, 0);
  }

  const int sel = tn >> 11;   // uniform per block
  if (sel < 2) {
    float* outp = sel ? kpre : qpre;
    const float* bias = sel ? bk : bq;
#pragma unroll
    for (int n = 0; n < 4; ++n) {
      int col = (tn & 2047) + wc * 64 + n * 16 + c;
      float bvv = bias[col];
#pragma unroll
      for (int m = 0; m < 4; ++m) {
        int row0 = tm + wr * 64 + m * 16 + g * 4;
#pragma unroll
        for (int i = 0; i < 4; ++i)
          outp[(size_t)(row0 + i) * 2048 + col] = acc[m][n][i] + bvv;
      }
    }
  } else {
#pragma unroll
    for (int n = 0; n < 4; ++n) {
      int colv = (tn - 4096) + wc * 64 + n * 16 + c;
      float bvv = bv[colv];
#pragma unroll
      for (int m = 0; m < 4; ++m) {
        int row0 = tm + wr * 64 + m * 16 + g * 4;
        uint2 o;
        o.x = pack2(acc[m][n][0] + bvv, acc[m][n][1] + bvv);
        o.y = pack2(acc[m][n][2] + bvv, acc[m][n][3] + bvv);
        *(uint2*)(Vt + (size_t)colv * S_ + row0) = o;
      }
    }
  }
}

// ---------------- Wo GEMM split-K=2, m97 structure -> fp32 partials ----------------
__global__ __launch_bounds__(256) void gemm_wo(const ushort* __restrict__ A,
                                               const ushort* __restrict__ B,
                                               float* __restrict__ pbuf, int K) {
  __shared__ __align__(16) unsigned char As[8192];
  __shared__ __align__(16) unsigned char Bs[8192];
  const int t = threadIdx.x, l = t & 63, w = t >> 6;
  const int g = l >> 4, c = l & 15;
  const int wr = w >> 1, wc = w & 1;

  const int orig = blockIdx.y * 16 + blockIdx.x;   // grid (16,32) = 512
  const int lin = (orig & 7) * 64 + (orig >> 3);
  const int bx = lin & 15, rest = lin >> 4;
  const int by = rest & 15, ks = rest >> 4;
  const int tm = by * 128, tn = bx * 128;
  const int k0 = ks * (K >> 1), k1 = k0 + (K >> 1);

  const int srow = t >> 2;
  const int schunk = (t & 3) ^ (srow & 3);
  const ushort* Ag = A + (size_t)(tm + srow) * K + schunk * 8;
  const ushort* Bg = B + (size_t)(tn + srow) * K + schunk * 8;
  const size_t rowK64 = (size_t)64 * K;
  void* As0 = (void*)(As + w * 1024);
  void* As1 = (void*)(As + 4096 + w * 1024);
  void* Bs0 = (void*)(Bs + w * 1024);
  void* Bs1 = (void*)(Bs + 4096 + w * 1024);

  f32x4 acc[4][4] = {};

  for (int kt = k0; kt < k1; kt += 32) {
    __syncthreads();
    gload_lds16(Ag + kt, As0);
    gload_lds16(Ag + rowK64 + kt, As1);
    gload_lds16(Bg + kt, Bs0);
    gload_lds16(Bg + rowK64 + kt, Bs1);
    __syncthreads();
    bf16x8 af[4], bfr[4];
#pragma unroll
    for (int m = 0; m < 4; ++m) {
      int row = wr * 64 + m * 16 + c;
      af[m] = *(const bf16x8*)(As + row * 64 + ((g ^ (row & 3)) << 4));
    }
#pragma unroll
    for (int n = 0; n < 4; ++n) {
      int row = wc * 64 + n * 16 + c;
      bfr[n] = *(const bf16x8*)(Bs + row * 64 + ((g ^ (row & 3)) << 4));
    }
#pragma unroll
    for (int m = 0; m < 4; ++m)
#pragma unroll
      for (int n = 0; n < 4; ++n)
        acc[m][n] = __builtin_amdgcn_mfma_f32_16x16x32_bf16(af[m], bfr[n], acc[m][n], 0, 0, 0);
  }

  float* out = pbuf + (size_t)ks * 2048 * 2048;
#pragma unroll
  for (int n = 0; n < 4; ++n) {
    int col = tn + wc * 64 + n * 16 + c;
#pragma unroll
    for (int m = 0; m < 4; ++m) {
      int row0 = tm + wr * 64 + m * 16 + g * 4;
#pragma unroll
      for (int i = 0; i < 4; ++i)
        out[(size_t)(row0 + i) * 2048 + col] = acc[m][n][i];
    }
  }
}

__global__ __launch_bounds__(256) void reduce_wo(const float* __restrict__ p,
                                                 const float* __restrict__ bo,
                                                 float* __restrict__ out, int n4) {
  int i = blockIdx.x * blockDim.x + threadIdx.x;
  if (i >= n4) return;
  float4 a = ((const float4*)p)[i];
  float4 b = ((const float4*)p)[i + n4];
  float4 bb = *(const float4*)(bo + ((i * 4) & 2047));
  float4 o;
  o.x = a.x + b.x + bb.x; o.y = a.y + b.y + bb.y;
  o.z = a.z + b.z + bb.z; o.w = a.w + b.w + bb.w;
  ((float4*)out)[i] = o;
}

// ---------------- fused rmsnorm + 3-axis RoPE + scale-fold, fp32 -> bf16 ----------------
// blockIdx.y: 0 -> q (fold=scale*log2e), 1 -> k (fold=1)
__global__ __launch_bounds__(256) void fuse_rms_rope(const float* __restrict__ qpre,
                                                     const float* __restrict__ kpre,
                                                     const float* __restrict__ gq,
                                                     const float* __restrict__ gk,
                                                     const float* __restrict__ fc,
                                                     const float* __restrict__ fs,
                                                     const int* __restrict__ pH,
                                                     const int* __restrict__ pW,
                                                     ushort* __restrict__ Qb,
                                                     ushort* __restrict__ Kb,
                                                     int dim, float foldq) {
  const int which = blockIdx.y;
  const float* pre = which ? kpre : qpre;
  const float* gw = which ? gk : gq;
  ushort* outp = which ? Kb : Qb;
  const float fold = which ? 1.0f : foldq;

  const int p = blockIdx.x, t = threadIdx.x;
  const float* row = pre + (size_t)p * dim;
  float v[8];
  {
    float4 a = *(const float4*)(row + t * 8);
    float4 b = *(const float4*)(row + t * 8 + 4);
    v[0] = a.x; v[1] = a.y; v[2] = a.z; v[3] = a.w;
    v[4] = b.x; v[5] = b.y; v[6] = b.z; v[7] = b.w;
  }
  float ss = 0.f;
#pragma unroll
  for (int i = 0; i < 8; ++i) ss += v[i] * v[i];
#pragma unroll
  for (int off = 32; off; off >>= 1) ss += __shfl_xor(ss, off);
  __shared__ float wsum[4];
  if ((t & 63) == 0) wsum[t >> 6] = ss;
  __syncthreads();
  float rstd = rsqrtf((wsum[0] + wsum[1] + wsum[2] + wsum[3]) * (1.0f / dim) + 1e-6f);
  float gv[8];
  {
    float4 a = *(const float4*)(gw + t * 8);
    float4 b = *(const float4*)(gw + t * 8 + 4);
    gv[0] = a.x; gv[1] = a.y; gv[2] = a.z; gv[3] = a.w;
    gv[4] = b.x; gv[5] = b.y; gv[6] = b.z; gv[7] = b.w;
  }
#pragma unroll
  for (int i = 0; i < 8; ++i) v[i] = v[i] * rstd * gv[i];

  const int H = pH[0], W = pW[0];
  const int hw = H * W;
  const int fr = p / hw;
  const int rem = p - fr * hw;
  const int hh = rem / W;
  const int ww = rem - hh * W;
  const int hd = dim / 16;
  const int cd = hd >> 1;
  const int c2 = cd / 3, c1 = cd - 2 * c2;
  const int j0 = ((t * 8) % hd) >> 1;

  uint ob[4];
#pragma unroll
  for (int q = 0; q < 4; ++q) {
    int j = j0 + q;
    int ri = (j < c1) ? fr : ((j < c1 + c2) ? hh : ww);
    float cs = fc[ri * cd + j];
    float sn = fs[ri * cd + j];
    float a = v[2 * q], b = v[2 * q + 1];
    ob[q] = pack2((a * cs - b * sn) * fold, (a * sn + b * cs) * fold);
  }
  uint4 o4; o4.x = ob[0]; o4.y = ob[1]; o4.z = ob[2]; o4.w = ob[3];
  *(uint4*)(outp + (size_t)p * dim + t * 8) = o4;
}

// ---------------- flash attention, 32x32 MFMA, 4 q-subtiles x 2 KV-splits ----------------
__global__ __launch_bounds__(512, 2) void attn32(const ushort* __restrict__ Qb,
                                                 const ushort* __restrict__ Kb,
                                                 const ushort* __restrict__ Vt,
                                                 ushort* __restrict__ Ob,
                                                 const int* __restrict__ seq_lens,
                                                 int S_, int DIMc) {
  __shared__ __align__(16) unsigned char smem[66560];
  float* mlbuf = (float*)(smem + 65536);
  const int t = threadIdx.x, l = t & 63, w = t >> 6;
  const int qsub = w & 3, ksp = w >> 2;
  const int h = l >> 5, ql = l & 31;

  const int orig = blockIdx.y * gridDim.x + blockIdx.x;
  const int nwg = gridDim.x * gridDim.y;
  const int lin = (orig & 7) * (nwg >> 3) + (orig >> 3);
  const int q0 = (lin % gridDim.x) * 128;
  const int head = lin / gridDim.x;
  const int kvlen = seq_lens[0];

  unsigned char* sk_s = smem + ksp * 16384;
  unsigned char* sv_s = smem + 32768 + ksp * 16384;

  bf16x8 qf[8];
  {
    const ushort* qp = Qb + (size_t)(q0 + qsub * 32 + ql) * DIMc + head * 128 + h * 8;
#pragma unroll
    for (int s = 0; s < 8; ++s) qf[s] = *(const bf16x8*)(qp + s * 16);
  }

  f32x16 ofr[4] = {};
  float m_run = -1e30f, l_run = 0.f;

  const int nt = (kvlen + 63) >> 6;
  const int half = (nt + 1) >> 1;
  const int tbase = ksp ? half : 0;
  const int mycnt = ksp ? (nt - half) : half;

  for (int tt = 0; tt < half; ++tt) {
    __syncthreads();
    if (tt < mycnt) {
      const int kv0 = (tbase + tt) * 64;
#pragma unroll
      for (int it = 0; it < 4; ++it) {
        int kr = qsub * 16 + it * 4 + (l >> 4);
        int kc = (l & 15) ^ (kr & 15);
        gload_lds16(Kb + (size_t)(kv0 + kr) * DIMc + head * 128 + kc * 8,
                    sk_s + qsub * 4096 + it * 1024);
        int vr = qsub * 32 + it * 8 + (l >> 3);
        int vc = (l & 7) ^ (vr & 7);
        gload_lds16(Vt + (size_t)(head * 128 + vr) * S_ + kv0 + vc * 8,
                    sv_s + qsub * 4096 + it * 1024);
      }
    }
    __syncthreads();
    if (tt >= mycnt) continue;
    const int kv0 = (tbase + tt) * 64;

    f32x16 sfr[2] = {};
#pragma unroll
    for (int kb = 0; kb < 2; ++kb) {
      const unsigned char* kbp = sk_s + (kb * 32 + ql) * 256;
      const int rx = (kb * 32 + ql) & 15;
#pragma unroll
      for (int s = 0; s < 8; ++s) {
        bf16x8 kf = *(const bf16x8*)(kbp + (((s * 2 + h) ^ rx) << 4));
        sfr[kb] = __builtin_amdgcn_mfma_f32_32x32x16_bf16(kf, qf[s], sfr[kb], 0, 0, 0);
      }
    }

    if (kv0 + 64 > kvlen) {
#pragma unroll
      for (int kb = 0; kb < 2; ++kb)
#pragma unroll
        for (int r = 0; r < 16; ++r) {
          int key = kv0 + kb * 32 + (r & 3) + 8 * (r >> 2) + 4 * h;
          if (key >= kvlen) sfr[kb][r] = -1e30f;
        }
    }

    float mt = -1e30f;
#pragma unroll
    for (int kb = 0; kb < 2; ++kb)
#pragma unroll
      for (int r = 0; r < 16; ++r) mt = fmaxf(mt, sfr[kb][r]);
    mt = fmaxf(mt, __shfl_xor(mt, 32));

    if (!__all(mt <= m_run + 8.0f)) {
      float m_new = fmaxf(m_run, mt);
      float fac = __builtin_amdgcn_exp2f(m_run - m_new);
      l_run *= fac;
#pragma unroll
      for (int df = 0; df < 4; ++df) ofr[df] *= fac;
      m_run = m_new;
    }

    float ls = 0.f;
    uint u[2][4][2];
#pragma unroll
    for (int kb = 0; kb < 2; ++kb)
#pragma unroll
      for (int G = 0; G < 4; ++G) {
        float p0 = __builtin_amdgcn_exp2f(sfr[kb][G * 4 + 0] - m_run);
        float p1 = __builtin_amdgcn_exp2f(sfr[kb][G * 4 + 1] - m_run);
        float p2 = __builtin_amdgcn_exp2f(sfr[kb][G * 4 + 2] - m_run);
        float p3 = __builtin_amdgcn_exp2f(sfr[kb][G * 4 + 3] - m_run);
        ls += (p0 + p1) + (p2 + p3);
        u[kb][G][0] = cvt_pk_bf16(p0, p1);
        u[kb][G][1] = cvt_pk_bf16(p2, p3);
      }
    ls += __shfl_xor(ls, 32);
    l_run += ls;

#pragma unroll
    for (int ks = 0; ks < 4; ++ks) {
      const int kb = ks >> 1, G0 = (ks & 1) * 2;
      uint own0 = h ? u[kb][G0 + 1][0] : u[kb][G0][0];
      uint own1 = h ? u[kb][G0 + 1][1] : u[kb][G0][1];
      uint snd0 = h ? u[kb][G0][0] : u[kb][G0 + 1][0];
      uint snd1 = h ? u[kb][G0][1] : u[kb][G0 + 1][1];
      uint rcv0 = __shfl_xor(snd0, 32);
      uint rcv1 = __shfl_xor(snd1, 32);
      union { uint4 q; bf16x8 b; } uu;
      uu.q.x = h ? rcv0 : own0;
      uu.q.y = h ? rcv1 : own1;
      uu.q.z = h ? own0 : rcv0;
      uu.q.w = h ? own1 : rcv1;
#pragma unroll
      for (int df = 0; df < 4; ++df) {
        const int row = df * 32 + ql;
        bf16x8 vf = *(const bf16x8*)(sv_s + row * 128 + (((ks * 2 + h) ^ (row & 7)) << 4));
        ofr[df] = __builtin_amdgcn_mfma_f32_32x32x16_bf16(vf, uu.b, ofr[df], 0, 0, 0);
      }
    }
  }

  __syncthreads();
  if (ksp == 1) {
    if (h == 0) { mlbuf[qsub * 64 + ql] = m_run; mlbuf[qsub * 64 + 32 + ql] = l_run; }
    float* ob = (float*)(smem + qsub * 16384);
#pragma unroll
    for (int df = 0; df < 4; ++df)
#pragma unroll
      for (int r = 0; r < 16; ++r) {
        int d = df * 32 + (r & 3) + 8 * (r >> 2) + 4 * h;
        ob[d * 32 + ql] = ofr[df][r];
      }
  }
  __syncthreads();
  if (ksp == 0) {
    float m2 = mlbuf[qsub * 64 + ql], l2 = mlbuf[qsub * 64 + 32 + ql];
    float mstar = fmaxf(m_run, m2);
    float f1 = __builtin_amdgcn_exp2f(m_run - mstar);
    float f2 = (l2 > 0.f) ? __builtin_amdgcn_exp2f(m2 - mstar) : 0.f;
    float lstar = l_run * f1 + l2 * f2;
    float inv = 1.0f / lstar;
    float a1 = f1 * inv, a2 = f2 * inv;
    const float* ob = (const float*)(smem + qsub * 16384);
    ushort* orow = Ob + (size_t)(q0 + qsub * 32 + ql) * DIMc + head * 128;
#pragma unroll
    for (int df = 0; df < 4; ++df)
#pragma unroll
      for (int G = 0; G < 4; ++G) {
        int d0 = df * 32 + 8 * G + 4 * h;
        float v0 = ofr[df][G * 4 + 0] * a1 + ob[(d0 + 0) * 32 + ql] * a2;
        float v1 = ofr[df][G * 4 + 1] * a1 + ob[(d0 + 1) * 32 + ql] * a2;
        float v2 = ofr[df][G * 4 + 2] * a1 + ob[(d0 + 2) * 32 + ql] * a2;
        float v3 = ofr[df][G * 4 + 3] * a1 + ob[(d0 + 3) * 32 + ql] * a2;
        uint2 o; o.x = pack2(v0, v1); o.y = pack2(v2, v3);
        *(uint2*)(orow + d0) = o;
      }
  }
}

// ---------------- host ----------------
extern "C" void kernel_launch(void* const* d_in, const int* in_sizes, int n_in,
                              void* d_out, int out_size, void* d_ws, size_t ws_size,
                              hipStream_t stream) {
  const float* x  = (const float*)d_in[0];
  const float* fc = (const float*)d_in[1];
  const float* fs = (const float*)d_in[2];
  const float* Wq = (const float*)d_in[3];
  const float* bq = (const float*)d_in[4];
  const float* Wk = (const float*)d_in[5];
  const float* bk = (const float*)d_in[6];
  const float* Wv = (const float*)d_in[7];
  const float* bv = (const float*)d_in[8];
  const float* Wo = (const float*)d_in[9];
  const float* bo = (const float*)d_in[10];
  const float* gq = (const float*)d_in[11];
  const float* gk = (const float*)d_in[12];
  const int* seq  = (const int*)d_in[13];
  const int* pH   = (const int*)d_in[15];
  const int* pW   = (const int*)d_in[16];

  const int DIMc = in_sizes[4];          // 2048
  const int S_   = in_sizes[0] / DIMc;   // 2048

  char* ws = (char*)d_ws;
  const size_t MB = 1024ull * 1024ull;
  ushort* xb    = (ushort*)(ws + 0 * MB);
  ushort* Wqkvb = (ushort*)(ws + 8 * MB);    // [6144][2048] bf16 = 24 MB
  ushort* Wob   = (ushort*)(ws + 32 * MB);
  float*  qpre  = (float*)(ws + 40 * MB);    // 16 MB
  float*  kpre  = (float*)(ws + 56 * MB);    // 16 MB
  ushort* Qb    = (ushort*)(ws + 72 * MB);
  ushort* Kb    = (ushort*)(ws + 80 * MB);
  ushort* Vt    = (ushort*)(ws + 88 * MB);
  ushort* Ob    = (ushort*)(ws + 40 * MB);   // aliases qpre (dead after fuse)
  float*  pbuf  = (float*)(ws + 56 * MB);    // 32 MB, aliases kpre/Qb/Kb (dead by then)

  const int nx8 = (S_ * DIMc) / 8;
  const int nw8 = (DIMc * DIMc) / 8;
  cvt_x<<<(nx8 + 255) / 256, 256, 0, stream>>>(x, xb, nx8);
  cvt_w4<<<dim3((nw8 + 255) / 256, 4), 256, 0, stream>>>(Wq, Wk, Wv, Wo, Wqkvb, Wob, nw8);

  gemm_qkv4<<<dim3(3 * DIMc / 128, S_ / 128), 256, 0, stream>>>(
      xb, Wqkvb, bq, bk, bv, qpre, kpre, Vt, DIMc, S_);

  const float foldq = LOG2E / sqrtf((float)(DIMc / 16));
  fuse_rms_rope<<<dim3(S_, 2), 256, 0, stream>>>(qpre, kpre, gq, gk, fc, fs, pH, pW,
                                                 Qb, Kb, DIMc, foldq);

  attn32<<<dim3(S_ / 128, 16), 512, 0, stream>>>(Qb, Kb, Vt, Ob, seq, S_, DIMc);

  gemm_wo<<<dim3(16, 32), 256, 0, stream>>>(Ob, Wob, pbuf, DIMc);
  reduce_wo<<<(S_ * DIMc / 4 + 255) / 256, 256, 0, stream>>>(pbuf, bo, (float*)d_out,
                                                             S_ * DIMc / 4);
}

// Round 4
// 224.209 us; speedup vs baseline: 1.0141x; 1.0141x over previous
//
#include <hip/hip_runtime.h>
#include <cstdint>
#include <cmath>

typedef unsigned int uint;
typedef unsigned short ushort;
typedef __bf16 bf16_t;
typedef bf16_t bf16x8 __attribute__((ext_vector_type(8)));
typedef float f32x4 __attribute__((ext_vector_type(4)));
typedef float f32x16 __attribute__((ext_vector_type(16)));

#define LOG2E 1.44269504088896340736f

__device__ __forceinline__ ushort f2bf(float f) {
  uint x = __float_as_uint(f);
  x += 0x7fffu + ((x >> 16) & 1u);   // RNE to bf16
  return (ushort)(x >> 16);
}
__device__ __forceinline__ uint pack2(float lo, float hi) {
  return (uint)f2bf(lo) | ((uint)f2bf(hi) << 16);
}
__device__ __forceinline__ uint cvt_pk_bf16(float lo, float hi) {
  uint r;
  asm("v_cvt_pk_bf16_f32 %0, %1, %2" : "=v"(r) : "v"(lo), "v"(hi));
  return r;
}

// global -> LDS direct copy, 16B per lane; LDS dest is wave-uniform base + lane*16.
__device__ __forceinline__ void gload_lds16(const void* gsrc, void* ldsdst) {
  typedef const __attribute__((address_space(1))) unsigned int* gp_t;
  typedef __attribute__((address_space(3))) unsigned int* lp_t;
  __builtin_amdgcn_global_load_lds((gp_t)(uintptr_t)gsrc,
                                   (lp_t)(unsigned int)(uintptr_t)ldsdst,
                                   16, 0, 0);
}

// ---------------- fp32 -> bf16 converts ----------------
__global__ __launch_bounds__(256) void cvt_x(const float* __restrict__ src,
                                             ushort* __restrict__ dst, int n8) {
  int i = blockIdx.x * blockDim.x + threadIdx.x;
  if (i >= n8) return;
  const float4* s4 = (const float4*)src;
  float4 a = s4[i * 2], b = s4[i * 2 + 1];
  uint4 o;
  o.x = pack2(a.x, a.y); o.y = pack2(a.z, a.w);
  o.z = pack2(b.x, b.y); o.w = pack2(b.z, b.w);
  ((uint4*)dst)[i] = o;
}

// 4 weight matrices in one launch: y=0..2 -> Wqkvb slices, y=3 -> Wob
__global__ __launch_bounds__(256) void cvt_w4(const float* __restrict__ s0,
                                              const float* __restrict__ s1,
                                              const float* __restrict__ s2,
                                              const float* __restrict__ s3,
                                              ushort* __restrict__ dA,
                                              ushort* __restrict__ dB, int n8) {
  const int y = blockIdx.y;
  const float* src = (y == 0) ? s0 : (y == 1) ? s1 : (y == 2) ? s2 : s3;
  ushort* dst = (y < 3) ? (dA + (size_t)y * n8 * 8) : dB;
  int i = blockIdx.x * blockDim.x + threadIdx.x;
  if (i >= n8) return;
  const float4* s4 = (const float4*)src;
  float4 a = s4[i * 2], b = s4[i * 2 + 1];
  uint4 o;
  o.x = pack2(a.x, a.y); o.y = pack2(a.z, a.w);
  o.z = pack2(b.x, b.y); o.w = pack2(b.z, b.w);
  ((uint4*)dst)[i] = o;
}

// ---------------- fused QKV GEMM, m97 structure: 256 thr, 4 waves, 64x64/wave ----------
// C[m][n] = sum_k A[m][k]*B[n][k]; B rows 0..2047=Wq, 2048..4095=Wk, 4096..6143=Wv.
// q/k pre-activations -> fp32; V -> bf16 written transposed (Vt[d][s]).
// NOTE: natural block order — R3's XCD swizzle caused 4x FETCH blow-up (each XCD
// streamed all of B through its private L2). Consecutive blocks share the A-panel.
__global__ __launch_bounds__(256) void gemm_qkv4(const ushort* __restrict__ A,
                                                 const ushort* __restrict__ B,
                                                 const float* __restrict__ bq,
                                                 const float* __restrict__ bk,
                                                 const float* __restrict__ bv,
                                                 float* __restrict__ qpre,
                                                 float* __restrict__ kpre,
                                                 ushort* __restrict__ Vt,
                                                 int K, int S_) {
  __shared__ __align__(16) unsigned char As[8192];
  __shared__ __align__(16) unsigned char Bs[8192];
  const int t = threadIdx.x, l = t & 63, w = t >> 6;
  const int g = l >> 4, c = l & 15;
  const int wr = w >> 1, wc = w & 1;
  const int tm = blockIdx.y * 128, tn = blockIdx.x * 128;

  const int srow = t >> 2;
  const int schunk = (t & 3) ^ (srow & 3);
  const ushort* Ag = A + (size_t)(tm + srow) * K + schunk * 8;
  const ushort* Bg = B + (size_t)(tn + srow) * K + schunk * 8;
  const size_t rowK64 = (size_t)64 * K;
  void* As0 = (void*)(As + w * 1024);
  void* As1 = (void*)(As + 4096 + w * 1024);
  void* Bs0 = (void*)(Bs + w * 1024);
  void* Bs1 = (void*)(Bs + 4096 + w * 1024);

  f32x4 acc[4][4] = {};

  for (int kt = 0; kt < K; kt += 32) {
    __syncthreads();
    gload_lds16(Ag + kt, As0);
    gload_lds16(Ag + rowK64 + kt, As1);
    gload_lds16(Bg + kt, Bs0);
    gload_lds16(Bg + rowK64 + kt, Bs1);
    __syncthreads();
    bf16x8 af[4], bfr[4];
#pragma unroll
    for (int m = 0; m < 4; ++m) {
      int row = wr * 64 + m * 16 + c;
      af[m] = *(const bf16x8*)(As + row * 64 + ((g ^ (row & 3)) << 4));
    }
#pragma unroll
    for (int n = 0; n < 4; ++n) {
      int row = wc * 64 + n * 16 + c;
      bfr[n] = *(const bf16x8*)(Bs + row * 64 + ((g ^ (row & 3)) << 4));
    }
#pragma unroll
    for (int m = 0; m < 4; ++m)
#pragma unroll
      for (int n = 0; n < 4; ++n)
        acc[m][n] = __builtin_amdgcn_mfma_f32_16x16x32_bf16(af[m], bfr[n], acc[m][n], 0, 0, 0);
  }

  const int sel = tn >> 11;   // uniform per block
  if (sel < 2) {
    float* outp = sel ? kpre : qpre;
    const float* bias = sel ? bk : bq;
#pragma unroll
    for (int n = 0; n < 4; ++n) {
      int col = (tn & 2047) + wc * 64 + n * 16 + c;
      float bvv = bias[col];
#pragma unroll
      for (int m = 0; m < 4; ++m) {
        int row0 = tm + wr * 64 + m * 16 + g * 4;
#pragma unroll
        for (int i = 0; i < 4; ++i)
          outp[(size_t)(row0 + i) * 2048 + col] = acc[m][n][i] + bvv;
      }
    }
  } else {
#pragma unroll
    for (int n = 0; n < 4; ++n) {
      int colv = (tn - 4096) + wc * 64 + n * 16 + c;
      float bvv = bv[colv];
#pragma unroll
      for (int m = 0; m < 4; ++m) {
        int row0 = tm + wr * 64 + m * 16 + g * 4;
        uint2 o;
        o.x = pack2(acc[m][n][0] + bvv, acc[m][n][1] + bvv);
        o.y = pack2(acc[m][n][2] + bvv, acc[m][n][3] + bvv);
        *(uint2*)(Vt + (size_t)colv * S_ + row0) = o;
      }
    }
  }
}

// ---------------- Wo GEMM split-K=2, m97 structure -> fp32 partials ----------------
// grid (16, 32): blockIdx.y & 15 = by, blockIdx.y >> 4 = k-split. Natural order.
__global__ __launch_bounds__(256) void gemm_wo(const ushort* __restrict__ A,
                                               const ushort* __restrict__ B,
                                               float* __restrict__ pbuf, int K) {
  __shared__ __align__(16) unsigned char As[8192];
  __shared__ __align__(16) unsigned char Bs[8192];
  const int t = threadIdx.x, l = t & 63, w = t >> 6;
  const int g = l >> 4, c = l & 15;
  const int wr = w >> 1, wc = w & 1;

  const int bx = blockIdx.x;
  const int by = blockIdx.y & 15, ks = blockIdx.y >> 4;
  const int tm = by * 128, tn = bx * 128;
  const int k0 = ks * (K >> 1), k1 = k0 + (K >> 1);

  const int srow = t >> 2;
  const int schunk = (t & 3) ^ (srow & 3);
  const ushort* Ag = A + (size_t)(tm + srow) * K + schunk * 8;
  const ushort* Bg = B + (size_t)(tn + srow) * K + schunk * 8;
  const size_t rowK64 = (size_t)64 * K;
  void* As0 = (void*)(As + w * 1024);
  void* As1 = (void*)(As + 4096 + w * 1024);
  void* Bs0 = (void*)(Bs + w * 1024);
  void* Bs1 = (void*)(Bs + 4096 + w * 1024);

  f32x4 acc[4][4] = {};

  for (int kt = k0; kt < k1; kt += 32) {
    __syncthreads();
    gload_lds16(Ag + kt, As0);
    gload_lds16(Ag + rowK64 + kt, As1);
    gload_lds16(Bg + kt, Bs0);
    gload_lds16(Bg + rowK64 + kt, Bs1);
    __syncthreads();
    bf16x8 af[4], bfr[4];
#pragma unroll
    for (int m = 0; m < 4; ++m) {
      int row = wr * 64 + m * 16 + c;
      af[m] = *(const bf16x8*)(As + row * 64 + ((g ^ (row & 3)) << 4));
    }
#pragma unroll
    for (int n = 0; n < 4; ++n) {
      int row = wc * 64 + n * 16 + c;
      bfr[n] = *(const bf16x8*)(Bs + row * 64 + ((g ^ (row & 3)) << 4));
    }
#pragma unroll
    for (int m = 0; m < 4; ++m)
#pragma unroll
      for (int n = 0; n < 4; ++n)
        acc[m][n] = __builtin_amdgcn_mfma_f32_16x16x32_bf16(af[m], bfr[n], acc[m][n], 0, 0, 0);
  }

  float* out = pbuf + (size_t)ks * 2048 * 2048;
#pragma unroll
  for (int n = 0; n < 4; ++n) {
    int col = tn + wc * 64 + n * 16 + c;
#pragma unroll
    for (int m = 0; m < 4; ++m) {
      int row0 = tm + wr * 64 + m * 16 + g * 4;
#pragma unroll
      for (int i = 0; i < 4; ++i)
        out[(size_t)(row0 + i) * 2048 + col] = acc[m][n][i];
    }
  }
}

__global__ __launch_bounds__(256) void reduce_wo(const float* __restrict__ p,
                                                 const float* __restrict__ bo,
                                                 float* __restrict__ out, int n4) {
  int i = blockIdx.x * blockDim.x + threadIdx.x;
  if (i >= n4) return;
  float4 a = ((const float4*)p)[i];
  float4 b = ((const float4*)p)[i + n4];
  float4 bb = *(const float4*)(bo + ((i * 4) & 2047));
  float4 o;
  o.x = a.x + b.x + bb.x; o.y = a.y + b.y + bb.y;
  o.z = a.z + b.z + bb.z; o.w = a.w + b.w + bb.w;
  ((float4*)out)[i] = o;
}

// ---------------- fused rmsnorm + 3-axis RoPE + scale-fold, fp32 -> bf16 ----------------
// blockIdx.y: 0 -> q (fold=scale*log2e), 1 -> k (fold=1)
__global__ __launch_bounds__(256) void fuse_rms_rope(const float* __restrict__ qpre,
                                                     const float* __restrict__ kpre,
                                                     const float* __restrict__ gq,
                                                     const float* __restrict__ gk,
                                                     const float* __restrict__ fc,
                                                     const float* __restrict__ fs,
                                                     const int* __restrict__ pH,
                                                     const int* __restrict__ pW,
                                                     ushort* __restrict__ Qb,
                                                     ushort* __restrict__ Kb,
                                                     int dim, float foldq) {
  const int which = blockIdx.y;
  const float* pre = which ? kpre : qpre;
  const float* gw = which ? gk : gq;
  ushort* outp = which ? Kb : Qb;
  const float fold = which ? 1.0f : foldq;

  const int p = blockIdx.x, t = threadIdx.x;
  const float* row = pre + (size_t)p * dim;
  float v[8];
  {
    float4 a = *(const float4*)(row + t * 8);
    float4 b = *(const float4*)(row + t * 8 + 4);
    v[0] = a.x; v[1] = a.y; v[2] = a.z; v[3] = a.w;
    v[4] = b.x; v[5] = b.y; v[6] = b.z; v[7] = b.w;
  }
  float ss = 0.f;
#pragma unroll
  for (int i = 0; i < 8; ++i) ss += v[i] * v[i];
#pragma unroll
  for (int off = 32; off; off >>= 1) ss += __shfl_xor(ss, off);
  __shared__ float wsum[4];
  if ((t & 63) == 0) wsum[t >> 6] = ss;
  __syncthreads();
  float rstd = rsqrtf((wsum[0] + wsum[1] + wsum[2] + wsum[3]) * (1.0f / dim) + 1e-6f);
  float gv[8];
  {
    float4 a = *(const float4*)(gw + t * 8);
    float4 b = *(const float4*)(gw + t * 8 + 4);
    gv[0] = a.x; gv[1] = a.y; gv[2] = a.z; gv[3] = a.w;
    gv[4] = b.x; gv[5] = b.y; gv[6] = b.z; gv[7] = b.w;
  }
#pragma unroll
  for (int i = 0; i < 8; ++i) v[i] = v[i] * rstd * gv[i];

  const int H = pH[0], W = pW[0];
  const int hw = H * W;
  const int fr = p / hw;
  const int rem = p - fr * hw;
  const int hh = rem / W;
  const int ww = rem - hh * W;
  const int hd = dim / 16;
  const int cd = hd >> 1;
  const int c2 = cd / 3, c1 = cd - 2 * c2;
  const int j0 = ((t * 8) % hd) >> 1;

  uint ob[4];
#pragma unroll
  for (int q = 0; q < 4; ++q) {
    int j = j0 + q;
    int ri = (j < c1) ? fr : ((j < c1 + c2) ? hh : ww);
    float cs = fc[ri * cd + j];
    float sn = fs[ri * cd + j];
    float a = v[2 * q], b = v[2 * q + 1];
    ob[q] = pack2((a * cs - b * sn) * fold, (a * sn + b * cs) * fold);
  }
  uint4 o4; o4.x = ob[0]; o4.y = ob[1]; o4.z = ob[2]; o4.w = ob[3];
  *(uint4*)(outp + (size_t)p * dim + t * 8) = o4;
}

// ---------------- flash attention, 32x32 MFMA, 4 q-subtiles x 2 KV-splits ----------------
__global__ __launch_bounds__(512, 2) void attn32(const ushort* __restrict__ Qb,
                                                 const ushort* __restrict__ Kb,
                                                 const ushort* __restrict__ Vt,
                                                 ushort* __restrict__ Ob,
                                                 const int* __restrict__ seq_lens,
                                                 int S_, int DIMc) {
  __shared__ __align__(16) unsigned char smem[66560];
  float* mlbuf = (float*)(smem + 65536);
  const int t = threadIdx.x, l = t & 63, w = t >> 6;
  const int qsub = w & 3, ksp = w >> 2;
  const int h = l >> 5, ql = l & 31;

  // head-major per-XCD grouping: per-XCD K/V working set = 2 heads ~ 2MB < 4MB L2
  const int orig = blockIdx.y * gridDim.x + blockIdx.x;
  const int nwg = gridDim.x * gridDim.y;
  const int lin = (orig & 7) * (nwg >> 3) + (orig >> 3);
  const int q0 = (lin % gridDim.x) * 128;
  const int head = lin / gridDim.x;
  const int kvlen = seq_lens[0];

  unsigned char* sk_s = smem + ksp * 16384;
  unsigned char* sv_s = smem + 32768 + ksp * 16384;

  bf16x8 qf[8];
  {
    const ushort* qp = Qb + (size_t)(q0 + qsub * 32 + ql) * DIMc + head * 128 + h * 8;
#pragma unroll
    for (int s = 0; s < 8; ++s) qf[s] = *(const bf16x8*)(qp + s * 16);
  }

  f32x16 ofr[4] = {};
  float m_run = -1e30f, l_run = 0.f;

  const int nt = (kvlen + 63) >> 6;
  const int half = (nt + 1) >> 1;
  const int tbase = ksp ? half : 0;
  const int mycnt = ksp ? (nt - half) : half;

  for (int tt = 0; tt < half; ++tt) {
    __syncthreads();
    if (tt < mycnt) {
      const int kv0 = (tbase + tt) * 64;
#pragma unroll
      for (int it = 0; it < 4; ++it) {
        int kr = qsub * 16 + it * 4 + (l >> 4);
        int kc = (l & 15) ^ (kr & 15);
        gload_lds16(Kb + (size_t)(kv0 + kr) * DIMc + head * 128 + kc * 8,
                    sk_s + qsub * 4096 + it * 1024);
        int vr = qsub * 32 + it * 8 + (l >> 3);
        int vc = (l & 7) ^ (vr & 7);
        gload_lds16(Vt + (size_t)(head * 128 + vr) * S_ + kv0 + vc * 8,
                    sv_s + qsub * 4096 + it * 1024);
      }
    }
    __syncthreads();
    if (tt >= mycnt) continue;
    const int kv0 = (tbase + tt) * 64;

    f32x16 sfr[2] = {};
#pragma unroll
    for (int kb = 0; kb < 2; ++kb) {
      const unsigned char* kbp = sk_s + (kb * 32 + ql) * 256;
      const int rx = (kb * 32 + ql) & 15;
#pragma unroll
      for (int s = 0; s < 8; ++s) {
        bf16x8 kf = *(const bf16x8*)(kbp + (((s * 2 + h) ^ rx) << 4));
        sfr[kb] = __builtin_amdgcn_mfma_f32_32x32x16_bf16(kf, qf[s], sfr[kb], 0, 0, 0);
      }
    }

    if (kv0 + 64 > kvlen) {
#pragma unroll
      for (int kb = 0; kb < 2; ++kb)
#pragma unroll
        for (int r = 0; r < 16; ++r) {
          int key = kv0 + kb * 32 + (r & 3) + 8 * (r >> 2) + 4 * h;
          if (key >= kvlen) sfr[kb][r] = -1e30f;
        }
    }

    float mt = -1e30f;
#pragma unroll
    for (int kb = 0; kb < 2; ++kb)
#pragma unroll
      for (int r = 0; r < 16; ++r) mt = fmaxf(mt, sfr[kb][r]);
    mt = fmaxf(mt, __shfl_xor(mt, 32));

    if (!__all(mt <= m_run + 8.0f)) {
      float m_new = fmaxf(m_run, mt);
      float fac = __builtin_amdgcn_exp2f(m_run - m_new);
      l_run *= fac;
#pragma unroll
      for (int df = 0; df < 4; ++df) ofr[df] *= fac;
      m_run = m_new;
    }

    float ls = 0.f;
    uint u[2][4][2];
#pragma unroll
    for (int kb = 0; kb < 2; ++kb)
#pragma unroll
      for (int G = 0; G < 4; ++G) {
        float p0 = __builtin_amdgcn_exp2f(sfr[kb][G * 4 + 0] - m_run);
        float p1 = __builtin_amdgcn_exp2f(sfr[kb][G * 4 + 1] - m_run);
        float p2 = __builtin_amdgcn_exp2f(sfr[kb][G * 4 + 2] - m_run);
        float p3 = __builtin_amdgcn_exp2f(sfr[kb][G * 4 + 3] - m_run);
        ls += (p0 + p1) + (p2 + p3);
        u[kb][G][0] = cvt_pk_bf16(p0, p1);
        u[kb][G][1] = cvt_pk_bf16(p2, p3);
      }
    ls += __shfl_xor(ls, 32);
    l_run += ls;

#pragma unroll
    for (int ks = 0; ks < 4; ++ks) {
      const int kb = ks >> 1, G0 = (ks & 1) * 2;
      uint own0 = h ? u[kb][G0 + 1][0] : u[kb][G0][0];
      uint own1 = h ? u[kb][G0 + 1][1] : u[kb][G0][1];
      uint snd0 = h ? u[kb][G0][0] : u[kb][G0 + 1][0];
      uint snd1 = h ? u[kb][G0][1] : u[kb][G0 + 1][1];
      uint rcv0 = __shfl_xor(snd0, 32);
      uint rcv1 = __shfl_xor(snd1, 32);
      union { uint4 q; bf16x8 b; } uu;
      uu.q.x = h ? rcv0 : own0;
      uu.q.y = h ? rcv1 : own1;
      uu.q.z = h ? own0 : rcv0;
      uu.q.w = h ? own1 : rcv1;
#pragma unroll
      for (int df = 0; df < 4; ++df) {
        const int row = df * 32 + ql;
        bf16x8 vf = *(const bf16x8*)(sv_s + row * 128 + (((ks * 2 + h) ^ (row & 7)) << 4));
        ofr[df] = __builtin_amdgcn_mfma_f32_32x32x16_bf16(vf, uu.b, ofr[df], 0, 0, 0);
      }
    }
  }

  __syncthreads();
  if (ksp == 1) {
    if (h == 0) { mlbuf[qsub * 64 + ql] = m_run; mlbuf[qsub * 64 + 32 + ql] = l_run; }
    float* ob = (float*)(smem + qsub * 16384);
#pragma unroll
    for (int df = 0; df < 4; ++df)
#pragma unroll
      for (int r = 0; r < 16; ++r) {
        int d = df * 32 + (r & 3) + 8 * (r >> 2) + 4 * h;
        ob[d * 32 + ql] = ofr[df][r];
      }
  }
  __syncthreads();
  if (ksp == 0) {
    float m2 = mlbuf[qsub * 64 + ql], l2 = mlbuf[qsub * 64 + 32 + ql];
    float mstar = fmaxf(m_run, m2);
    float f1 = __builtin_amdgcn_exp2f(m_run - mstar);
    float f2 = (l2 > 0.f) ? __builtin_amdgcn_exp2f(m2 - mstar) : 0.f;
    float lstar = l_run * f1 + l2 * f2;
    float inv = 1.0f / lstar;
    float a1 = f1 * inv, a2 = f2 * inv;
    const float* ob = (const float*)(smem + qsub * 16384);
    ushort* orow = Ob + (size_t)(q0 + qsub * 32 + ql) * DIMc + head * 128;
#pragma unroll
    for (int df = 0; df < 4; ++df)
#pragma unroll
      for (int G = 0; G < 4; ++G) {
        int d0 = df * 32 + 8 * G + 4 * h;
        float v0 = ofr[df][G * 4 + 0] * a1 + ob[(d0 + 0) * 32 + ql] * a2;
        float v1 = ofr[df][G * 4 + 1] * a1 + ob[(d0 + 1) * 32 + ql] * a2;
        float v2 = ofr[df][G * 4 + 2] * a1 + ob[(d0 + 2) * 32 + ql] * a2;
        float v3 = ofr[df][G * 4 + 3] * a1 + ob[(d0 + 3) * 32 + ql] * a2;
        uint2 o; o.x = pack2(v0, v1); o.y = pack2(v2, v3);
        *(uint2*)(orow + d0) = o;
      }
  }
}

// ---------------- host ----------------
extern "C" void kernel_launch(void* const* d_in, const int* in_sizes, int n_in,
                              void* d_out, int out_size, void* d_ws, size_t ws_size,
                              hipStream_t stream) {
  const float* x  = (const float*)d_in[0];
  const float* fc = (const float*)d_in[1];
  const float* fs = (const float*)d_in[2];
  const float* Wq = (const float*)d_in[3];
  const float* bq = (const float*)d_in[4];
  const float* Wk = (const float*)d_in[5];
  const float* bk = (const float*)d_in[6];
  const float* Wv = (const float*)d_in[7];
  const float* bv = (const float*)d_in[8];
  const float* Wo = (const float*)d_in[9];
  const float* bo = (const float*)d_in[10];
  const float* gq = (const float*)d_in[11];
  const float* gk = (const float*)d_in[12];
  const int* seq  = (const int*)d_in[13];
  const int* pH   = (const int*)d_in[15];
  const int* pW   = (const int*)d_in[16];

  const int DIMc = in_sizes[4];          // 2048
  const int S_   = in_sizes[0] / DIMc;   // 2048

  char* ws = (char*)d_ws;
  const size_t MB = 1024ull * 1024ull;
  ushort* xb    = (ushort*)(ws + 0 * MB);
  ushort* Wqkvb = (ushort*)(ws + 8 * MB);    // [6144][2048] bf16 = 24 MB
  ushort* Wob   = (ushort*)(ws + 32 * MB);
  float*  qpre  = (float*)(ws + 40 * MB);    // 16 MB
  float*  kpre  = (float*)(ws + 56 * MB);    // 16 MB
  ushort* Qb    = (ushort*)(ws + 72 * MB);
  ushort* Kb    = (ushort*)(ws + 80 * MB);
  ushort* Vt    = (ushort*)(ws + 88 * MB);
  ushort* Ob    = (ushort*)(ws + 40 * MB);   // aliases qpre (dead after fuse)
  float*  pbuf  = (float*)(ws + 56 * MB);    // 32 MB, aliases kpre/Qb/Kb (dead by then)

  const int nx8 = (S_ * DIMc) / 8;
  const int nw8 = (DIMc * DIMc) / 8;
  cvt_x<<<(nx8 + 255) / 256, 256, 0, stream>>>(x, xb, nx8);
  cvt_w4<<<dim3((nw8 + 255) / 256, 4), 256, 0, stream>>>(Wq, Wk, Wv, Wo, Wqkvb, Wob, nw8);

  gemm_qkv4<<<dim3(3 * DIMc / 128, S_ / 128), 256, 0, stream>>>(
      xb, Wqkvb, bq, bk, bv, qpre, kpre, Vt, DIMc, S_);

  const float foldq = LOG2E / sqrtf((float)(DIMc / 16));
  fuse_rms_rope<<<dim3(S_, 2), 256, 0, stream>>>(qpre, kpre, gq, gk, fc, fs, pH, pW,
                                                 Qb, Kb, DIMc, foldq);

  attn32<<<dim3(S_ / 128, 16), 512, 0, stream>>>(Qb, Kb, Vt, Ob, seq, S_, DIMc);

  gemm_wo<<<dim3(16, 32), 256, 0, stream>>>(Ob, Wob, pbuf, DIMc);
  reduce_wo<<<(S_ * DIMc / 4 + 255) / 256, 256, 0, stream>>>(pbuf, bo, (float*)d_out,
                                                             S_ * DIMc / 4);
}

// Round 5
// 190.032 us; speedup vs baseline: 1.1965x; 1.1799x over previous
//
#include <hip/hip_runtime.h>
#include <cstdint>
#include <cmath>

typedef unsigned int uint;
typedef unsigned short ushort;
typedef __bf16 bf16_t;
typedef bf16_t bf16x8 __attribute__((ext_vector_type(8)));
typedef float f32x4 __attribute__((ext_vector_type(4)));
typedef float f32x16 __attribute__((ext_vector_type(16)));

#define LOG2E 1.44269504088896340736f

__device__ __forceinline__ ushort f2bf(float f) {
  uint x = __float_as_uint(f);
  x += 0x7fffu + ((x >> 16) & 1u);   // RNE to bf16
  return (ushort)(x >> 16);
}
__device__ __forceinline__ uint pack2(float lo, float hi) {
  return (uint)f2bf(lo) | ((uint)f2bf(hi) << 16);
}
__device__ __forceinline__ uint cvt_pk_bf16(float lo, float hi) {
  uint r;
  asm("v_cvt_pk_bf16_f32 %0, %1, %2" : "=v"(r) : "v"(lo), "v"(hi));
  return r;
}

// global -> LDS direct copy, 16B per lane; LDS dest is wave-uniform base + lane*16.
__device__ __forceinline__ void gload_lds16(const void* gsrc, void* ldsdst) {
  typedef const __attribute__((address_space(1))) unsigned int* gp_t;
  typedef __attribute__((address_space(3))) unsigned int* lp_t;
  __builtin_amdgcn_global_load_lds((gp_t)(uintptr_t)gsrc,
                                   (lp_t)(unsigned int)(uintptr_t)ldsdst,
                                   16, 0, 0);
}

// ---------------- fp32 -> bf16 converts ----------------
__global__ __launch_bounds__(256) void cvt_x(const float* __restrict__ src,
                                             ushort* __restrict__ dst, int n8) {
  int i = blockIdx.x * blockDim.x + threadIdx.x;
  if (i >= n8) return;
  const float4* s4 = (const float4*)src;
  float4 a = s4[i * 2], b = s4[i * 2 + 1];
  uint4 o;
  o.x = pack2(a.x, a.y); o.y = pack2(a.z, a.w);
  o.z = pack2(b.x, b.y); o.w = pack2(b.z, b.w);
  ((uint4*)dst)[i] = o;
}

// 4 weight matrices in one launch: y=0..2 -> Wqkvb slices, y=3 -> Wob
__global__ __launch_bounds__(256) void cvt_w4(const float* __restrict__ s0,
                                              const float* __restrict__ s1,
                                              const float* __restrict__ s2,
                                              const float* __restrict__ s3,
                                              ushort* __restrict__ dA,
                                              ushort* __restrict__ dB, int n8) {
  const int y = blockIdx.y;
  const float* src = (y == 0) ? s0 : (y == 1) ? s1 : (y == 2) ? s2 : s3;
  ushort* dst = (y < 3) ? (dA + (size_t)y * n8 * 8) : dB;
  int i = blockIdx.x * blockDim.x + threadIdx.x;
  if (i >= n8) return;
  const float4* s4 = (const float4*)src;
  float4 a = s4[i * 2], b = s4[i * 2 + 1];
  uint4 o;
  o.x = pack2(a.x, a.y); o.y = pack2(a.z, a.w);
  o.z = pack2(b.x, b.y); o.w = pack2(b.z, b.w);
  ((uint4*)dst)[i] = o;
}

// ---------------- fused QKV GEMM (8 waves, 512 thr, 128x128 tile, BK=32) -----------
// Proven 74.7us/687TF on this shape (R2). Wave tile 32x64 (4x2 wave grid).
// B rows 0..2047=Wq, 2048..4095=Wk, 4096..6143=Wv. q/k -> fp32; V -> bf16 transposed.
__global__ __launch_bounds__(512) void gemm_qkv(const ushort* __restrict__ A,
                                                const ushort* __restrict__ B,
                                                const float* __restrict__ bq,
                                                const float* __restrict__ bk,
                                                const float* __restrict__ bv,
                                                float* __restrict__ qpre,
                                                float* __restrict__ kpre,
                                                ushort* __restrict__ Vt,
                                                int K, int S_) {
  __shared__ __align__(16) unsigned char As[8192];
  __shared__ __align__(16) unsigned char Bs[8192];
  const int t = threadIdx.x, l = t & 63, w = t >> 6;
  const int g = l >> 4, c = l & 15;
  const int wr = w >> 1, wc = w & 1;
  const int tm = blockIdx.y * 128, tn = blockIdx.x * 128;

  const int srow = w * 16 + (l >> 2);
  const int schunk = (l & 3) ^ (srow & 3);
  const ushort* Ag = A + (size_t)(tm + srow) * K + schunk * 8;
  const ushort* Bg = B + (size_t)(tn + srow) * K + schunk * 8;
  void* AsBase = (void*)(As + w * 1024);
  void* BsBase = (void*)(Bs + w * 1024);

  f32x4 acc[2][4] = {};

  for (int kt = 0; kt < K; kt += 32) {
    __syncthreads();
    gload_lds16(Ag + kt, AsBase);
    gload_lds16(Bg + kt, BsBase);
    __syncthreads();
    bf16x8 af[2], bfr[4];
#pragma unroll
    for (int m = 0; m < 2; ++m) {
      int row = wr * 32 + m * 16 + c;
      af[m] = *(const bf16x8*)(As + row * 64 + ((g ^ (row & 3)) << 4));
    }
#pragma unroll
    for (int n = 0; n < 4; ++n) {
      int row = wc * 64 + n * 16 + c;
      bfr[n] = *(const bf16x8*)(Bs + row * 64 + ((g ^ (row & 3)) << 4));
    }
#pragma unroll
    for (int m = 0; m < 2; ++m)
#pragma unroll
      for (int n = 0; n < 4; ++n)
        acc[m][n] = __builtin_amdgcn_mfma_f32_16x16x32_bf16(af[m], bfr[n], acc[m][n], 0, 0, 0);
  }

  const int sel = tn >> 11;   // uniform per block
  if (sel < 2) {
    float* outp = sel ? kpre : qpre;
    const float* bias = sel ? bk : bq;
#pragma unroll
    for (int n = 0; n < 4; ++n) {
      int col = (tn & 2047) + wc * 64 + n * 16 + c;
      float bvv = bias[col];
#pragma unroll
      for (int m = 0; m < 2; ++m) {
        int row0 = tm + wr * 32 + m * 16 + g * 4;
#pragma unroll
        for (int i = 0; i < 4; ++i)
          outp[(size_t)(row0 + i) * 2048 + col] = acc[m][n][i] + bvv;
      }
    }
  } else {
#pragma unroll
    for (int n = 0; n < 4; ++n) {
      int colv = (tn - 4096) + wc * 64 + n * 16 + c;
      float bvv = bv[colv];
#pragma unroll
      for (int m = 0; m < 2; ++m) {
        int row0 = tm + wr * 32 + m * 16 + g * 4;
        uint2 o;
        o.x = pack2(acc[m][n][0] + bvv, acc[m][n][1] + bvv);
        o.y = pack2(acc[m][n][2] + bvv, acc[m][n][3] + bvv);
        *(uint2*)(Vt + (size_t)colv * S_ + row0) = o;
      }
    }
  }
}

// ---------------- Wo GEMM split-K=2, 8 waves (same structure) -> fp32 partials ------
// grid (16, 16, 2); blockIdx.z = k-split. 512 blocks -> ~16 waves/CU.
__global__ __launch_bounds__(512) void gemm_wo(const ushort* __restrict__ A,
                                               const ushort* __restrict__ B,
                                               float* __restrict__ pbuf, int K) {
  __shared__ __align__(16) unsigned char As[8192];
  __shared__ __align__(16) unsigned char Bs[8192];
  const int t = threadIdx.x, l = t & 63, w = t >> 6;
  const int g = l >> 4, c = l & 15;
  const int wr = w >> 1, wc = w & 1;
  const int tm = blockIdx.y * 128, tn = blockIdx.x * 128;
  const int ks = blockIdx.z;
  const int k0 = ks * (K >> 1), k1 = k0 + (K >> 1);

  const int srow = w * 16 + (l >> 2);
  const int schunk = (l & 3) ^ (srow & 3);
  const ushort* Ag = A + (size_t)(tm + srow) * K + schunk * 8;
  const ushort* Bg = B + (size_t)(tn + srow) * K + schunk * 8;
  void* AsBase = (void*)(As + w * 1024);
  void* BsBase = (void*)(Bs + w * 1024);

  f32x4 acc[2][4] = {};

  for (int kt = k0; kt < k1; kt += 32) {
    __syncthreads();
    gload_lds16(Ag + kt, AsBase);
    gload_lds16(Bg + kt, BsBase);
    __syncthreads();
    bf16x8 af[2], bfr[4];
#pragma unroll
    for (int m = 0; m < 2; ++m) {
      int row = wr * 32 + m * 16 + c;
      af[m] = *(const bf16x8*)(As + row * 64 + ((g ^ (row & 3)) << 4));
    }
#pragma unroll
    for (int n = 0; n < 4; ++n) {
      int row = wc * 64 + n * 16 + c;
      bfr[n] = *(const bf16x8*)(Bs + row * 64 + ((g ^ (row & 3)) << 4));
    }
#pragma unroll
    for (int m = 0; m < 2; ++m)
#pragma unroll
      for (int n = 0; n < 4; ++n)
        acc[m][n] = __builtin_amdgcn_mfma_f32_16x16x32_bf16(af[m], bfr[n], acc[m][n], 0, 0, 0);
  }

  float* out = pbuf + (size_t)ks * 2048 * 2048;
#pragma unroll
  for (int n = 0; n < 4; ++n) {
    int col = tn + wc * 64 + n * 16 + c;
#pragma unroll
    for (int m = 0; m < 2; ++m) {
      int row0 = tm + wr * 32 + m * 16 + g * 4;
#pragma unroll
      for (int i = 0; i < 4; ++i)
        out[(size_t)(row0 + i) * 2048 + col] = acc[m][n][i];
    }
  }
}

__global__ __launch_bounds__(256) void reduce_wo(const float* __restrict__ p,
                                                 const float* __restrict__ bo,
                                                 float* __restrict__ out, int n4) {
  int i = blockIdx.x * blockDim.x + threadIdx.x;
  if (i >= n4) return;
  float4 a = ((const float4*)p)[i];
  float4 b = ((const float4*)p)[i + n4];
  float4 bb = *(const float4*)(bo + ((i * 4) & 2047));
  float4 o;
  o.x = a.x + b.x + bb.x; o.y = a.y + b.y + bb.y;
  o.z = a.z + b.z + bb.z; o.w = a.w + b.w + bb.w;
  ((float4*)out)[i] = o;
}

// ---------------- fused rmsnorm + 3-axis RoPE + scale-fold, fp32 -> bf16 ----------------
// blockIdx.y: 0 -> q (fold=scale*log2e), 1 -> k (fold=1)
__global__ __launch_bounds__(256) void fuse_rms_rope(const float* __restrict__ qpre,
                                                     const float* __restrict__ kpre,
                                                     const float* __restrict__ gq,
                                                     const float* __restrict__ gk,
                                                     const float* __restrict__ fc,
                                                     const float* __restrict__ fs,
                                                     const int* __restrict__ pH,
                                                     const int* __restrict__ pW,
                                                     ushort* __restrict__ Qb,
                                                     ushort* __restrict__ Kb,
                                                     int dim, float foldq) {
  const int which = blockIdx.y;
  const float* pre = which ? kpre : qpre;
  const float* gw = which ? gk : gq;
  ushort* outp = which ? Kb : Qb;
  const float fold = which ? 1.0f : foldq;

  const int p = blockIdx.x, t = threadIdx.x;
  const float* row = pre + (size_t)p * dim;
  float v[8];
  {
    float4 a = *(const float4*)(row + t * 8);
    float4 b = *(const float4*)(row + t * 8 + 4);
    v[0] = a.x; v[1] = a.y; v[2] = a.z; v[3] = a.w;
    v[4] = b.x; v[5] = b.y; v[6] = b.z; v[7] = b.w;
  }
  float ss = 0.f;
#pragma unroll
  for (int i = 0; i < 8; ++i) ss += v[i] * v[i];
#pragma unroll
  for (int off = 32; off; off >>= 1) ss += __shfl_xor(ss, off);
  __shared__ float wsum[4];
  if ((t & 63) == 0) wsum[t >> 6] = ss;
  __syncthreads();
  float rstd = rsqrtf((wsum[0] + wsum[1] + wsum[2] + wsum[3]) * (1.0f / dim) + 1e-6f);
  float gv[8];
  {
    float4 a = *(const float4*)(gw + t * 8);
    float4 b = *(const float4*)(gw + t * 8 + 4);
    gv[0] = a.x; gv[1] = a.y; gv[2] = a.z; gv[3] = a.w;
    gv[4] = b.x; gv[5] = b.y; gv[6] = b.z; gv[7] = b.w;
  }
#pragma unroll
  for (int i = 0; i < 8; ++i) v[i] = v[i] * rstd * gv[i];

  const int H = pH[0], W = pW[0];
  const int hw = H * W;
  const int fr = p / hw;
  const int rem = p - fr * hw;
  const int hh = rem / W;
  const int ww = rem - hh * W;
  const int hd = dim / 16;
  const int cd = hd >> 1;
  const int c2 = cd / 3, c1 = cd - 2 * c2;
  const int j0 = ((t * 8) % hd) >> 1;

  uint ob[4];
#pragma unroll
  for (int q = 0; q < 4; ++q) {
    int j = j0 + q;
    int ri = (j < c1) ? fr : ((j < c1 + c2) ? hh : ww);
    float cs = fc[ri * cd + j];
    float sn = fs[ri * cd + j];
    float a = v[2 * q], b = v[2 * q + 1];
    ob[q] = pack2((a * cs - b * sn) * fold, (a * sn + b * cs) * fold);
  }
  uint4 o4; o4.x = ob[0]; o4.y = ob[1]; o4.z = ob[2]; o4.w = ob[3];
  *(uint4*)(outp + (size_t)p * dim + t * 8) = o4;
}

// ---------------- flash attention, 32x32 MFMA, 4 q-subtiles x 2 KV-splits ----------------
__global__ __launch_bounds__(512, 2) void attn32(const ushort* __restrict__ Qb,
                                                 const ushort* __restrict__ Kb,
                                                 const ushort* __restrict__ Vt,
                                                 ushort* __restrict__ Ob,
                                                 const int* __restrict__ seq_lens,
                                                 int S_, int DIMc) {
  __shared__ __align__(16) unsigned char smem[66560];
  float* mlbuf = (float*)(smem + 65536);
  const int t = threadIdx.x, l = t & 63, w = t >> 6;
  const int qsub = w & 3, ksp = w >> 2;
  const int h = l >> 5, ql = l & 31;

  // head-major per-XCD grouping: per-XCD K/V working set = 2 heads ~ 2MB < 4MB L2
  const int orig = blockIdx.y * gridDim.x + blockIdx.x;
  const int nwg = gridDim.x * gridDim.y;
  const int lin = (orig & 7) * (nwg >> 3) + (orig >> 3);
  const int q0 = (lin % gridDim.x) * 128;
  const int head = lin / gridDim.x;
  const int kvlen = seq_lens[0];

  unsigned char* sk_s = smem + ksp * 16384;
  unsigned char* sv_s = smem + 32768 + ksp * 16384;

  bf16x8 qf[8];
  {
    const ushort* qp = Qb + (size_t)(q0 + qsub * 32 + ql) * DIMc + head * 128 + h * 8;
#pragma unroll
    for (int s = 0; s < 8; ++s) qf[s] = *(const bf16x8*)(qp + s * 16);
  }

  f32x16 ofr[4] = {};
  float m_run = -1e30f, l_run = 0.f;

  const int nt = (kvlen + 63) >> 6;
  const int half = (nt + 1) >> 1;
  const int tbase = ksp ? half : 0;
  const int mycnt = ksp ? (nt - half) : half;

  for (int tt = 0; tt < half; ++tt) {
    __syncthreads();
    if (tt < mycnt) {
      const int kv0 = (tbase + tt) * 64;
#pragma unroll
      for (int it = 0; it < 4; ++it) {
        int kr = qsub * 16 + it * 4 + (l >> 4);
        int kc = (l & 15) ^ (kr & 15);
        gload_lds16(Kb + (size_t)(kv0 + kr) * DIMc + head * 128 + kc * 8,
                    sk_s + qsub * 4096 + it * 1024);
        int vr = qsub * 32 + it * 8 + (l >> 3);
        int vc = (l & 7) ^ (vr & 7);
        gload_lds16(Vt + (size_t)(head * 128 + vr) * S_ + kv0 + vc * 8,
                    sv_s + qsub * 4096 + it * 1024);
      }
    }
    __syncthreads();
    if (tt >= mycnt) continue;
    const int kv0 = (tbase + tt) * 64;

    f32x16 sfr[2] = {};
    __builtin_amdgcn_s_setprio(1);
#pragma unroll
    for (int kb = 0; kb < 2; ++kb) {
      const unsigned char* kbp = sk_s + (kb * 32 + ql) * 256;
      const int rx = (kb * 32 + ql) & 15;
#pragma unroll
      for (int s = 0; s < 8; ++s) {
        bf16x8 kf = *(const bf16x8*)(kbp + (((s * 2 + h) ^ rx) << 4));
        sfr[kb] = __builtin_amdgcn_mfma_f32_32x32x16_bf16(kf, qf[s], sfr[kb], 0, 0, 0);
      }
    }
    __builtin_amdgcn_s_setprio(0);

    if (kv0 + 64 > kvlen) {
#pragma unroll
      for (int kb = 0; kb < 2; ++kb)
#pragma unroll
        for (int r = 0; r < 16; ++r) {
          int key = kv0 + kb * 32 + (r & 3) + 8 * (r >> 2) + 4 * h;
          if (key >= kvlen) sfr[kb][r] = -1e30f;
        }
    }

    float mt = -1e30f;
#pragma unroll
    for (int kb = 0; kb < 2; ++kb)
#pragma unroll
      for (int r = 0; r < 16; ++r) mt = fmaxf(mt, sfr[kb][r]);
    mt = fmaxf(mt, __shfl_xor(mt, 32));

    if (!__all(mt <= m_run + 8.0f)) {
      float m_new = fmaxf(m_run, mt);
      float fac = __builtin_amdgcn_exp2f(m_run - m_new);
      l_run *= fac;
#pragma unroll
      for (int df = 0; df < 4; ++df) ofr[df] *= fac;
      m_run = m_new;
    }

    float ls = 0.f;
    uint u[2][4][2];
#pragma unroll
    for (int kb = 0; kb < 2; ++kb)
#pragma unroll
      for (int G = 0; G < 4; ++G) {
        float p0 = __builtin_amdgcn_exp2f(sfr[kb][G * 4 + 0] - m_run);
        float p1 = __builtin_amdgcn_exp2f(sfr[kb][G * 4 + 1] - m_run);
        float p2 = __builtin_amdgcn_exp2f(sfr[kb][G * 4 + 2] - m_run);
        float p3 = __builtin_amdgcn_exp2f(sfr[kb][G * 4 + 3] - m_run);
        ls += (p0 + p1) + (p2 + p3);
        u[kb][G][0] = cvt_pk_bf16(p0, p1);
        u[kb][G][1] = cvt_pk_bf16(p2, p3);
      }
    ls += __shfl_xor(ls, 32);
    l_run += ls;

#pragma unroll
    for (int ks = 0; ks < 4; ++ks) {
      const int kb = ks >> 1, G0 = (ks & 1) * 2;
      uint own0 = h ? u[kb][G0 + 1][0] : u[kb][G0][0];
      uint own1 = h ? u[kb][G0 + 1][1] : u[kb][G0][1];
      uint snd0 = h ? u[kb][G0][0] : u[kb][G0 + 1][0];
      uint snd1 = h ? u[kb][G0][1] : u[kb][G0 + 1][1];
      uint rcv0 = __shfl_xor(snd0, 32);
      uint rcv1 = __shfl_xor(snd1, 32);
      union { uint4 q; bf16x8 b; } uu;
      uu.q.x = h ? rcv0 : own0;
      uu.q.y = h ? rcv1 : own1;
      uu.q.z = h ? own0 : rcv0;
      uu.q.w = h ? own1 : rcv1;
      __builtin_amdgcn_s_setprio(1);
#pragma unroll
      for (int df = 0; df < 4; ++df) {
        const int row = df * 32 + ql;
        bf16x8 vf = *(const bf16x8*)(sv_s + row * 128 + (((ks * 2 + h) ^ (row & 7)) << 4));
        ofr[df] = __builtin_amdgcn_mfma_f32_32x32x16_bf16(vf, uu.b, ofr[df], 0, 0, 0);
      }
      __builtin_amdgcn_s_setprio(0);
    }
  }

  __syncthreads();
  if (ksp == 1) {
    if (h == 0) { mlbuf[qsub * 64 + ql] = m_run; mlbuf[qsub * 64 + 32 + ql] = l_run; }
    float* ob = (float*)(smem + qsub * 16384);
#pragma unroll
    for (int df = 0; df < 4; ++df)
#pragma unroll
      for (int r = 0; r < 16; ++r) {
        int d = df * 32 + (r & 3) + 8 * (r >> 2) + 4 * h;
        ob[d * 32 + ql] = ofr[df][r];
      }
  }
  __syncthreads();
  if (ksp == 0) {
    float m2 = mlbuf[qsub * 64 + ql], l2 = mlbuf[qsub * 64 + 32 + ql];
    float mstar = fmaxf(m_run, m2);
    float f1 = __builtin_amdgcn_exp2f(m_run - mstar);
    float f2 = (l2 > 0.f) ? __builtin_amdgcn_exp2f(m2 - mstar) : 0.f;
    float lstar = l_run * f1 + l2 * f2;
    float inv = 1.0f / lstar;
    float a1 = f1 * inv, a2 = f2 * inv;
    const float* ob = (const float*)(smem + qsub * 16384);
    ushort* orow = Ob + (size_t)(q0 + qsub * 32 + ql) * DIMc + head * 128;
#pragma unroll
    for (int df = 0; df < 4; ++df)
#pragma unroll
      for (int G = 0; G < 4; ++G) {
        int d0 = df * 32 + 8 * G + 4 * h;
        float v0 = ofr[df][G * 4 + 0] * a1 + ob[(d0 + 0) * 32 + ql] * a2;
        float v1 = ofr[df][G * 4 + 1] * a1 + ob[(d0 + 1) * 32 + ql] * a2;
        float v2 = ofr[df][G * 4 + 2] * a1 + ob[(d0 + 2) * 32 + ql] * a2;
        float v3 = ofr[df][G * 4 + 3] * a1 + ob[(d0 + 3) * 32 + ql] * a2;
        uint2 o; o.x = pack2(v0, v1); o.y = pack2(v2, v3);
        *(uint2*)(orow + d0) = o;
      }
  }
}

// ---------------- host ----------------
extern "C" void kernel_launch(void* const* d_in, const int* in_sizes, int n_in,
                              void* d_out, int out_size, void* d_ws, size_t ws_size,
                              hipStream_t stream) {
  const float* x  = (const float*)d_in[0];
  const float* fc = (const float*)d_in[1];
  const float* fs = (const float*)d_in[2];
  const float* Wq = (const float*)d_in[3];
  const float* bq = (const float*)d_in[4];
  const float* Wk = (const float*)d_in[5];
  const float* bk = (const float*)d_in[6];
  const float* Wv = (const float*)d_in[7];
  const float* bv = (const float*)d_in[8];
  const float* Wo = (const float*)d_in[9];
  const float* bo = (const float*)d_in[10];
  const float* gq = (const float*)d_in[11];
  const float* gk = (const float*)d_in[12];
  const int* seq  = (const int*)d_in[13];
  const int* pH   = (const int*)d_in[15];
  const int* pW   = (const int*)d_in[16];

  const int DIMc = in_sizes[4];          // 2048
  const int S_   = in_sizes[0] / DIMc;   // 2048

  char* ws = (char*)d_ws;
  const size_t MB = 1024ull * 1024ull;
  ushort* xb    = (ushort*)(ws + 0 * MB);
  ushort* Wqkvb = (ushort*)(ws + 8 * MB);    // [6144][2048] bf16 = 24 MB
  ushort* Wob   = (ushort*)(ws + 32 * MB);
  float*  qpre  = (float*)(ws + 40 * MB);    // 16 MB
  float*  kpre  = (float*)(ws + 56 * MB);    // 16 MB
  ushort* Qb    = (ushort*)(ws + 72 * MB);
  ushort* Kb    = (ushort*)(ws + 80 * MB);
  ushort* Vt    = (ushort*)(ws + 88 * MB);
  ushort* Ob    = (ushort*)(ws + 40 * MB);   // aliases qpre (dead after fuse)
  float*  pbuf  = (float*)(ws + 56 * MB);    // 32 MB, aliases kpre/Qb/Kb (dead by then)

  const int nx8 = (S_ * DIMc) / 8;
  const int nw8 = (DIMc * DIMc) / 8;
  cvt_x<<<(nx8 + 255) / 256, 256, 0, stream>>>(x, xb, nx8);
  cvt_w4<<<dim3((nw8 + 255) / 256, 4), 256, 0, stream>>>(Wq, Wk, Wv, Wo, Wqkvb, Wob, nw8);

  gemm_qkv<<<dim3(3 * DIMc / 128, S_ / 128), 512, 0, stream>>>(
      xb, Wqkvb, bq, bk, bv, qpre, kpre, Vt, DIMc, S_);

  const float foldq = LOG2E / sqrtf((float)(DIMc / 16));
  fuse_rms_rope<<<dim3(S_, 2), 256, 0, stream>>>(qpre, kpre, gq, gk, fc, fs, pH, pW,
                                                 Qb, Kb, DIMc, foldq);

  attn32<<<dim3(S_ / 128, 16), 512, 0, stream>>>(Qb, Kb, Vt, Ob, seq, S_, DIMc);

  gemm_wo<<<dim3(16, 16, 2), 512, 0, stream>>>(Ob, Wob, pbuf, DIMc);
  reduce_wo<<<(S_ * DIMc / 4 + 255) / 256, 256, 0, stream>>>(pbuf, bo, (float*)d_out,
                                                             S_ * DIMc / 4);
}